// Round 16
// baseline (185.272 us; speedup 1.0000x reference)
//
#include <hip/hip_runtime.h>

#define T_DIM 4096
#define J_DIM 24
#define NCI 16
#define NCO 16
#define G_DIM 75
#define WAVE_T 256   // t-elements per wave (64 lanes x 4); 16 waves cover 4096

// Inverse of ALL_IDX: for each original joint j, the output g-positions that
// replicate it (conv kernel height is 1, so gathered rows are pure copies).
__device__ const int d_nrep[J_DIM] = {4,3,3,3,3,3,3,3,3,5,3,3,3,3,3,3,3,3,3,3,3,3,3,3};
__device__ const int d_repl[J_DIM][5] = {
  {0, 9, 12, 15, -1},
  {1, 10, 18, -1, -1},
  {2, 13, 21, -1, -1},
  {3, 16, 24, -1, -1},
  {11, 19, 27, -1, -1},
  {14, 22, 30, -1, -1},
  {17, 25, 33, -1, -1},
  {20, 28, 38, -1, -1},
  {23, 31, 40, -1, -1},
  {26, 34, 42, 45, 48},
  {4, 29, 39, -1, -1},
  {5, 32, 41, -1, -1},
  {35, 43, 51, -1, -1},
  {36, 46, 53, -1, -1},
  {37, 49, 56, -1, -1},
  {6, 44, 52, -1, -1},
  {47, 54, 59, -1, -1},
  {50, 57, 62, -1, -1},
  {55, 60, 65, -1, -1},
  {58, 63, 68, -1, -1},
  {61, 66, 71, -1, -1},
  {64, 69, 73, -1, -1},
  {7, 67, 72, -1, -1},
  {8, 70, 74, -1, -1},
};

// 1024-thread block = 16 waves spanning the FULL t=4096 row.
// Per-wave code identical to the 177µs R13 kernel; only block shape differs.
// -> lockstep store phase emits each (co,g) row as one 16KB contiguous
//    coordinated burst (16 waves x adjacent 1KB), and the 16 waves'
//    reads of each x row coalesce into 16KB bursts too.
__global__ __launch_bounds__(1024, 4) void skel_conv(
    const float* __restrict__ x, const float* __restrict__ W,
    const float* __restrict__ bias, float* __restrict__ out) {
  const int j    = blockIdx.y;   // original joint
  const int b    = blockIdx.z;   // batch
  const int tid  = (int)threadIdx.x;
  const int lane = tid & 63;
  // Each WAVE owns a private 256-t slice and computes ALL 16 out-channels
  // -> no two waves anywhere read the same x cache line.
  const int wv = __builtin_amdgcn_readfirstlane(tid >> 6);  // 0..15

  const int t0 = wv * WAVE_T + lane * 4;

  // acc[co], initialized with bias (block-uniform scalar loads)
  float4 acc[NCO];
#pragma unroll
  for (int co = 0; co < NCO; ++co) {
    const float bb = bias[co];
    acc[co] = make_float4(bb, bb, bb, bb);
  }

#pragma unroll 2
  for (int ci = 0; ci < NCI; ++ci) {
    const float* xp = x + (((size_t)b * NCI + ci) * J_DIM + j) * T_DIM;
    const float4 v = *(const float4*)(xp + t0);
    // t-halo via in-wave shuffle; wave-edge lanes patch with a direct load
    float xm1 = __shfl_up(v.w, 1);    // x[t0-1]
    float xp4 = __shfl_down(v.x, 1);  // x[t0+4]
    if (lane == 0)  xm1 = (t0 > 0) ? xp[t0 - 1] : 0.f;
    if (lane == 63) xp4 = (t0 + 4 < T_DIM) ? xp[t0 + 4] : 0.f;

#pragma unroll
    for (int co = 0; co < NCO; ++co) {
      // uniform indices -> s_load; SGPR operands in the FMAs
      const float w0 = W[(co * NCI + ci) * 3 + 0];
      const float w1 = W[(co * NCI + ci) * 3 + 1];
      const float w2 = W[(co * NCI + ci) * 3 + 2];
      acc[co].x = fmaf(xm1, w0, fmaf(v.x, w1, fmaf(v.y, w2, acc[co].x)));
      acc[co].y = fmaf(v.x, w0, fmaf(v.y, w1, fmaf(v.z, w2, acc[co].y)));
      acc[co].z = fmaf(v.y, w0, fmaf(v.z, w1, fmaf(v.w, w2, acc[co].z)));
      acc[co].w = fmaf(v.z, w0, fmaf(v.w, w1, fmaf(xp4, w2, acc[co].w)));
    }
  }

  // Lockstep store phase: all 16 waves enter together, so the 16 adjacent
  // 1KB pieces of each (co,g) row form one 16KB contiguous burst.
  __syncthreads();

  // co-outer / r-inner: consecutive row-bursts are 48-144KB apart.
  const int nrep = d_nrep[j];
  float* ob = out + (size_t)b * NCO * G_DIM * T_DIM + t0;
#pragma unroll
  for (int co = 0; co < NCO; ++co) {
    float* oc = ob + (size_t)co * (G_DIM * T_DIM);
    for (int r = 0; r < nrep; ++r) {
      const int g = d_repl[j][r];
      *(float4*)(oc + (size_t)g * T_DIM) = acc[co];
    }
  }
}

extern "C" void kernel_launch(void* const* d_in, const int* in_sizes, int n_in,
                              void* d_out, int out_size, void* d_ws, size_t ws_size,
                              hipStream_t stream) {
  const float* x    = (const float*)d_in[0];
  const float* W    = (const float*)d_in[1];
  const float* bias = (const float*)d_in[2];
  float* out = (float*)d_out;

  dim3 grid(1, J_DIM, 32);  // 24 x 32 = 768 blocks of 16 waves
  dim3 block(1024);
  skel_conv<<<grid, block, 0, stream>>>(x, W, bias, out);
}